// Round 6
// baseline (1848.581 us; speedup 1.0000x reference)
//
#include <hip/hip_runtime.h>

#define H_DIM 256
#define NLAYER 5
#define BGRAPH 1024
#define CAP 24

typedef __attribute__((ext_vector_type(8))) short short8;
typedef __attribute__((ext_vector_type(4))) float f32x4;
typedef const __attribute__((address_space(1))) unsigned int* gas_ptr;
typedef __attribute__((address_space(3))) unsigned int* las_ptr;

// ---- bf16 helpers (storage-only; math fp32 / MFMA-fp32-accum) ----
struct __align__(8) us4 { unsigned short x, y, z, w; };

__device__ __forceinline__ float b2f(unsigned short u) {
    union { float f; unsigned v; } c; c.v = ((unsigned)u) << 16; return c.f;
}
__device__ __forceinline__ unsigned short f2b(float f) {
    union { float f; unsigned v; } c; c.f = f;
    return (unsigned short)((c.v + 0x7fffu + ((c.v >> 16) & 1u)) >> 16);
}

// ---------------------------------------------------------------- embed ----
__global__ __launch_bounds__(256) void embed_kernel(
    const float* __restrict__ x, const float* __restrict__ W,
    const float* __restrict__ b, unsigned short* __restrict__ h, int K)
{
    __shared__ float xs[256];            // 8 rows * K (K <= 32)
    const int m0 = blockIdx.x * 8;
    const int tid = threadIdx.x;
    if (tid < 8 * K) xs[tid] = x[(size_t)m0 * K + tid];
    __syncthreads();
    const int n = tid;
    float acc[8] = {0.f,0.f,0.f,0.f,0.f,0.f,0.f,0.f};
    for (int k = 0; k < K; ++k) {
        const float w = W[k * H_DIM + n];
        #pragma unroll
        for (int r = 0; r < 8; ++r) acc[r] += xs[r * K + k] * w;
    }
    const float bb = b[n];
    #pragma unroll
    for (int r = 0; r < 8; ++r)
        h[(size_t)(m0 + r) * H_DIM + n] = f2b(acc[r] + bb);
}

// ---------------------------------------------------------------- init v ---
__global__ __launch_bounds__(256) void init_v_kernel(
    const float* __restrict__ lig0, const float* __restrict__ prot0,
    float* __restrict__ lig_v, float* __restrict__ prot_v)
{
    const int b = blockIdx.x, n = threadIdx.x;
    lig_v[b * H_DIM + n]  = lig0[n];
    prot_v[b * H_DIM + n] = prot0[n];
}

// ------------------------------------------------- weight prep -------------
// Wt[l][n][k'] = bf16(W[l][k][n]) with per-row k-chunk permutation so that
// linear global_load_lds staging + XOR-swizzled fragment reads are
// bank-conflict-free: chunk slot s holds k-chunk (s ^ ((n>>1)&3)).
__global__ __launch_bounds__(256) void wprep_kernel(
    const float* __restrict__ W, unsigned short* __restrict__ Wt)
{
    __shared__ float t[64][65];
    const int l = blockIdx.z;
    const int k0 = blockIdx.x * 64, n0 = blockIdx.y * 64;
    const int tid = threadIdx.x;
    const int c = tid & 63, r4 = tid >> 6;
    const float* Wl = W + (size_t)l * 65536;
    unsigned short* Wtl = Wt + (size_t)l * 65536;
    #pragma unroll
    for (int i = 0; i < 16; ++i) {
        const int r = i * 4 + r4;                       // k-local
        t[r][c] = Wl[(size_t)(k0 + r) * 256 + n0 + c];  // c = n-local
    }
    __syncthreads();
    #pragma unroll
    for (int i = 0; i < 16; ++i) {
        const int nn = i * 4 + r4;                      // n-local
        const int n = n0 + nn;
        const int x = (n >> 1) & 3;
        const int s = ((c >> 3) & 3) ^ x;               // c = k-local here
        const int kaddr = k0 + (c & ~31) + (s << 3) + (c & 7);
        Wtl[(size_t)n * 256 + kaddr] = f2b(t[c][nn]);
    }
}

// ------------------------------------------------------- bucket build ------
__global__ __launch_bounds__(256) void bucket_build_kernel(
    const int* __restrict__ src, const int* __restrict__ dst, int E,
    int* __restrict__ deg, int* __restrict__ bucket)
{
    const int e = blockIdx.x * 256 + threadIdx.x;
    if (e >= E) return;
    const int d = dst[e], s = src[e];
    const int slot = atomicAdd(&deg[d], 1);
    if (slot < CAP) bucket[(size_t)d * CAP + slot] = s;
}

// ------------------------------------------------------------ pool (v+=) ---
__global__ __launch_bounds__(256) void pool_add_kernel(
    const unsigned short* __restrict__ h, float* __restrict__ v, int cnt)
{
    const int b = blockIdx.x, n = threadIdx.x;
    const unsigned short* hp = &h[(size_t)b * cnt * H_DIM + n];
    float s = 0.f;
    #pragma unroll 8
    for (int r = 0; r < cnt; ++r) s += b2f(hp[(size_t)r * H_DIM]);
    v[b * H_DIM + n] += s;
}

// --------------------------------------------------------- v += hsum -------
__global__ __launch_bounds__(256) void v_add_kernel(
    float* __restrict__ v, const float* __restrict__ hsum)
{
    const int idx = blockIdx.x * 256 + threadIdx.x;
    v[idx] += hsum[idx];
}

// ----------------------------------------------------- small fp32 GEMM -----
template<bool RELU>
__global__ __launch_bounds__(256) void gemm_small_kernel(
    const float* __restrict__ A, const float* __restrict__ W,
    const float* __restrict__ bias, float* __restrict__ C,
    int M, int N, int K)
{
    constexpr int BM = 32, BN = 64, BK = 32, TM = 2;
    __shared__ __align__(16) float As[BK][BM + 4];
    __shared__ __align__(16) float Bs[BK][BN];
    const int tid = threadIdx.x;
    const int tx = tid & 15;
    const int ty = tid >> 4;
    const int m0 = blockIdx.x * BM;
    const int n0 = blockIdx.y * BN;

    float acc[TM][4] = {};

    for (int kt = 0; kt < K; kt += BK) {
        {
            const int row = tid >> 3, kq = tid & 7;
            const float4 a = *(const float4*)&A[(size_t)(m0 + row) * K + kt + kq * 4];
            As[kq * 4 + 0][row] = a.x;
            As[kq * 4 + 1][row] = a.y;
            As[kq * 4 + 2][row] = a.z;
            As[kq * 4 + 3][row] = a.w;
        }
        #pragma unroll
        for (int i = 0; i < 2; ++i) {
            const int f = tid + i * 256;
            const int row = f >> 4, c4 = f & 15;
            *(float4*)&Bs[row][c4 * 4] =
                *(const float4*)&W[(size_t)(kt + row) * N + n0 + c4 * 4];
        }
        __syncthreads();
        #pragma unroll
        for (int kk = 0; kk < BK; ++kk) {
            const float4 bv = *(const float4*)&Bs[kk][tx * 4];
            #pragma unroll
            for (int im = 0; im < TM; ++im) {
                const float a = As[kk][ty * TM + im];
                acc[im][0] += a * bv.x; acc[im][1] += a * bv.y;
                acc[im][2] += a * bv.z; acc[im][3] += a * bv.w;
            }
        }
        __syncthreads();
    }

    const float4 bb = *(const float4*)&bias[n0 + tx * 4];
    #pragma unroll
    for (int im = 0; im < TM; ++im) {
        const int m = m0 + ty * TM + im;
        float4 r;
        r.x = acc[im][0] + bb.x; r.y = acc[im][1] + bb.y;
        r.z = acc[im][2] + bb.z; r.w = acc[im][3] + bb.w;
        if constexpr (RELU) {
            r.x = fmaxf(r.x, 0.f); r.y = fmaxf(r.y, 0.f);
            r.z = fmaxf(r.z, 0.f); r.w = fmaxf(r.w, 0.f);
        }
        *(float4*)&C[(size_t)m * N + n0 + tx * 4] = r;
    }
}

// --------------------------------------------- fused gather+conv MFMA ------
// Per 64-row block (one graph):
//   phase 0: gather z rows = (Hin[m]+v[g]) + sum_nb (Hin[s]+v[batch[s]])
//            into XOR-swizzled LDS A-tile (bf16)
//   phase 1: t = relu(z @ W1 + b1) -> Ts (LDS, padded)
//   phase 2: o = t @ W2 + b2
//   phase 3: Hout[m] = (Hin[m]+v[g]) + o ; hsum[g] += column sums (pool)
// Wt1/Wt2 are pre-swizzled (wprep). 512 threads = 8 waves (2x4 of 32x64).
__global__ __launch_bounds__(512) void conv_fused2_kernel(
    const unsigned short* __restrict__ Hin,
    const int* __restrict__ deg, const int* __restrict__ bucket,
    const int* __restrict__ batch, const float* __restrict__ v,
    const unsigned short* __restrict__ Wt1, const float* __restrict__ b1,
    const unsigned short* __restrict__ Wt2, const float* __restrict__ b2,
    unsigned short* __restrict__ Hout, float* __restrict__ hsum)
{
    constexpr int K = 256, BK = 32;
    __shared__ __align__(16) unsigned short U[64 * 264];   // Ah(swz) / Ts union
    __shared__ __align__(16) unsigned short Bs[256 * 32];
    const int tid  = threadIdx.x;
    const int lane = tid & 63;
    const int wid  = tid >> 6;
    const int wr   = wid >> 2;
    const int wc   = wid & 3;
    const int q    = lane >> 4;
    const int l15  = lane & 15;
    const int m0   = blockIdx.x * 64;
    const int albase = (tid & ~63) * 16;
    const int bq0  = batch[m0];                 // whole block = one graph
    const float* __restrict__ vg = v + (size_t)bq0 * H_DIM;

    // ---------------- phase 0: gather ----------------
    {
        const float4 vm = *(const float4*)&vg[lane * 4];
        for (int r8 = 0; r8 < 8; ++r8) {
            const int lr = wid * 8 + r8;
            const int m = m0 + lr;
            const us4 hv = *(const us4*)&Hin[(size_t)m * H_DIM + lane * 4];
            float4 acc = { b2f(hv.x) + vm.x, b2f(hv.y) + vm.y,
                           b2f(hv.z) + vm.z, b2f(hv.w) + vm.w };
            int cnt = deg[m]; if (cnt > CAP) cnt = CAP;
            const int* bp = &bucket[(size_t)m * CAP];
            for (int i = 0; i < cnt; i += 4) {
                const int4 s4 = *(const int4*)&bp[i];
                const int rem = cnt - i;
                us4 a0, a1, a2, a3;
                int q0, q1, q2, q3;
                a0 = *(const us4*)&Hin[(size_t)s4.x * H_DIM + lane * 4];
                q0 = batch[s4.x];
                if (rem > 1) { a1 = *(const us4*)&Hin[(size_t)s4.y * H_DIM + lane * 4]; q1 = batch[s4.y]; }
                if (rem > 2) { a2 = *(const us4*)&Hin[(size_t)s4.z * H_DIM + lane * 4]; q2 = batch[s4.z]; }
                if (rem > 3) { a3 = *(const us4*)&Hin[(size_t)s4.w * H_DIM + lane * 4]; q3 = batch[s4.w]; }
                {
                    const float4 w0 = *(const float4*)&v[(size_t)q0 * H_DIM + lane * 4];
                    acc.x += b2f(a0.x) + w0.x; acc.y += b2f(a0.y) + w0.y;
                    acc.z += b2f(a0.z) + w0.z; acc.w += b2f(a0.w) + w0.w;
                }
                if (rem > 1) {
                    const float4 w1 = *(const float4*)&v[(size_t)q1 * H_DIM + lane * 4];
                    acc.x += b2f(a1.x) + w1.x; acc.y += b2f(a1.y) + w1.y;
                    acc.z += b2f(a1.z) + w1.z; acc.w += b2f(a1.w) + w1.w;
                }
                if (rem > 2) {
                    const float4 w2 = *(const float4*)&v[(size_t)q2 * H_DIM + lane * 4];
                    acc.x += b2f(a2.x) + w2.x; acc.y += b2f(a2.y) + w2.y;
                    acc.z += b2f(a2.z) + w2.z; acc.w += b2f(a2.w) + w2.w;
                }
                if (rem > 3) {
                    const float4 w3 = *(const float4*)&v[(size_t)q3 * H_DIM + lane * 4];
                    acc.x += b2f(a3.x) + w3.x; acc.y += b2f(a3.y) + w3.y;
                    acc.z += b2f(a3.z) + w3.z; acc.w += b2f(a3.w) + w3.w;
                }
            }
            us4 o = { f2b(acc.x), f2b(acc.y), f2b(acc.z), f2b(acc.w) };
            const int ab = lr * 512 + ((lane * 8) ^ ((lr & 7) << 4));
            *(us4*)((char*)U + ab) = o;
        }
    }
    __syncthreads();

    f32x4 acc[2][4];
    #pragma unroll
    for (int i = 0; i < 2; ++i)
        #pragma unroll
        for (int j = 0; j < 4; ++j) acc[i][j] = (f32x4){0.f, 0.f, 0.f, 0.f};

    // ---------------- phase 1: GEMM1 (A from swizzled U) ----------------
    for (int kt = 0; kt < K; kt += BK) {
        #pragma unroll
        for (int i = 0; i < 2; ++i) {
            const int c = tid + i * 512;
            __builtin_amdgcn_global_load_lds(
                (gas_ptr)&Wt1[(size_t)(c >> 2) * K + kt + (c & 3) * 8],
                (las_ptr)((char*)Bs + albase + i * 8192), 16, 0, 0);
        }
        __syncthreads();
        short8 av[2], bv[4];
        #pragma unroll
        for (int mi = 0; mi < 2; ++mi) {
            const int lrow = wr * 32 + mi * 16 + l15;
            const int ab = lrow * 512 + ((kt * 2 + q * 16) ^ ((lrow & 7) << 4));
            av[mi] = *(const short8*)((char*)U + ab);
        }
        #pragma unroll
        for (int ni = 0; ni < 4; ++ni) {
            const int n = wc * 64 + ni * 16 + l15;
            const int bb = n * 64 + ((q * 16) ^ (((n >> 1) & 3) << 4));
            bv[ni] = *(const short8*)((char*)Bs + bb);
        }
        #pragma unroll
        for (int mi = 0; mi < 2; ++mi)
            #pragma unroll
            for (int ni = 0; ni < 4; ++ni)
                acc[mi][ni] = __builtin_amdgcn_mfma_f32_16x16x32_bf16(
                    av[mi], bv[ni], acc[mi][ni], 0, 0, 0);
        __syncthreads();
    }

    // bias + relu -> Ts (U reused; Ah dead)
    #pragma unroll
    for (int ni = 0; ni < 4; ++ni) {
        const int col = wc * 64 + ni * 16 + l15;
        const float bb = b1[col];
        #pragma unroll
        for (int mi = 0; mi < 2; ++mi)
            #pragma unroll
            for (int j = 0; j < 4; ++j) {
                const int row = wr * 32 + mi * 16 + q * 4 + j;
                U[row * 264 + col] = f2b(fmaxf(acc[mi][ni][j] + bb, 0.f));
            }
    }
    #pragma unroll
    for (int i = 0; i < 2; ++i)
        #pragma unroll
        for (int j = 0; j < 4; ++j) acc[i][j] = (f32x4){0.f, 0.f, 0.f, 0.f};
    __syncthreads();

    // ---------------- phase 2: GEMM2 (A from Ts) ----------------
    for (int kt = 0; kt < K; kt += BK) {
        #pragma unroll
        for (int i = 0; i < 2; ++i) {
            const int c = tid + i * 512;
            __builtin_amdgcn_global_load_lds(
                (gas_ptr)&Wt2[(size_t)(c >> 2) * K + kt + (c & 3) * 8],
                (las_ptr)((char*)Bs + albase + i * 8192), 16, 0, 0);
        }
        __syncthreads();
        short8 av[2], bv[4];
        #pragma unroll
        for (int mi = 0; mi < 2; ++mi) {
            const int lrow = wr * 32 + mi * 16 + l15;
            av[mi] = *(const short8*)&U[lrow * 264 + kt + q * 8];
        }
        #pragma unroll
        for (int ni = 0; ni < 4; ++ni) {
            const int n = wc * 64 + ni * 16 + l15;
            const int bb = n * 64 + ((q * 16) ^ (((n >> 1) & 3) << 4));
            bv[ni] = *(const short8*)((char*)Bs + bb);
        }
        #pragma unroll
        for (int mi = 0; mi < 2; ++mi)
            #pragma unroll
            for (int ni = 0; ni < 4; ++ni)
                acc[mi][ni] = __builtin_amdgcn_mfma_f32_16x16x32_bf16(
                    av[mi], bv[ni], acc[mi][ni], 0, 0, 0);
        __syncthreads();
    }

    // ---------------- phase 3: epilogue + pooled column sums ----------------
    float* hl = (float*)Bs;                 // Bs dead; 1 KB column accumulator
    if (tid < 256) hl[tid] = 0.f;
    __syncthreads();

    int cols[4]; float b2c[4], vc[4];
    #pragma unroll
    for (int ni = 0; ni < 4; ++ni) {
        cols[ni] = wc * 64 + ni * 16 + l15;
        b2c[ni] = b2[cols[ni]];
        vc[ni]  = vg[cols[ni]];
    }
    float lsum[4] = {0.f, 0.f, 0.f, 0.f};
    #pragma unroll
    for (int mi = 0; mi < 2; ++mi)
        #pragma unroll
        for (int j = 0; j < 4; ++j) {
            const int row = m0 + wr * 32 + mi * 16 + q * 4 + j;
            const unsigned short* hip_ = &Hin[(size_t)row * H_DIM];
            unsigned short* hop = &Hout[(size_t)row * H_DIM];
            #pragma unroll
            for (int ni = 0; ni < 4; ++ni) {
                const float val = b2f(hip_[cols[ni]]) + vc[ni]
                                + acc[mi][ni][j] + b2c[ni];
                hop[cols[ni]] = f2b(val);
                lsum[ni] += val;
            }
        }
    #pragma unroll
    for (int ni = 0; ni < 4; ++ni) atomicAdd(&hl[cols[ni]], lsum[ni]);
    __syncthreads();
    if (tid < 256) atomicAdd(&hsum[(size_t)bq0 * H_DIM + tid], hl[tid]);
}

// ------------------------------------------------------------- BN split ----
__global__ __launch_bounds__(256) void bn_part_kernel(
    const float* __restrict__ vtmp, float* __restrict__ part)
{
    const int g = blockIdx.x, n = threadIdx.x;
    float s = 0.f, s2 = 0.f;
    #pragma unroll 8
    for (int r = 0; r < 32; ++r) {
        const float x = vtmp[(size_t)(g * 32 + r) * H_DIM + n];
        s += x; s2 += x * x;
    }
    part[g * H_DIM + n] = s;
    part[32 * H_DIM + g * H_DIM + n] = s2;
}

__global__ __launch_bounds__(256) void bn_finalize_kernel(
    const float* __restrict__ part, const float* __restrict__ gamma,
    const float* __restrict__ beta, float* __restrict__ scale,
    float* __restrict__ shift)
{
    const int n = threadIdx.x;
    float s = 0.f, s2 = 0.f;
    #pragma unroll 8
    for (int g = 0; g < 32; ++g) {
        s  += part[g * H_DIM + n];
        s2 += part[32 * H_DIM + g * H_DIM + n];
    }
    const float mean = s * (1.f / BGRAPH);
    const float var  = s2 * (1.f / BGRAPH) - mean * mean;
    const float sc   = gamma[n] * rsqrtf(var + 1e-5f);
    scale[n] = sc;
    shift[n] = beta[n] - mean * sc;
}

__global__ __launch_bounds__(256) void bn_relu_kernel(
    const float* __restrict__ vtmp, const float* __restrict__ scale,
    const float* __restrict__ shift, float* __restrict__ v)
{
    const int idx = blockIdx.x * 256 + threadIdx.x;
    const int n = idx & 255;
    v[idx] = fmaxf(vtmp[idx] * scale[n] + shift[n], 0.f);
}

// ------------------------------------------------- readout from hsum -------
__global__ __launch_bounds__(256) void pool_hsum_kernel(
    const float* __restrict__ hl, const float* __restrict__ hp,
    float* __restrict__ comb)
{
    const int b = blockIdx.x, n = threadIdx.x;
    comb[(size_t)b * 512 + n]       = hl[(size_t)b * H_DIM + n] * (1.f / 64.f);
    comb[(size_t)b * 512 + 256 + n] = hp[(size_t)b * H_DIM + n] * (1.f / 128.f);
}

// ------------------------------------------------------------ final dot ----
__global__ __launch_bounds__(256) void pred_final_kernel(
    const float* __restrict__ hidden, const float* __restrict__ W2,
    const float* __restrict__ b2, float* __restrict__ out)
{
    const int b = blockIdx.x, t = threadIdx.x;
    float p = hidden[(size_t)b * H_DIM + t] * W2[t];
    #pragma unroll
    for (int off = 32; off >= 1; off >>= 1) p += __shfl_down(p, off);
    __shared__ float red[4];
    if ((t & 63) == 0) red[t >> 6] = p;
    __syncthreads();
    if (t == 0) out[b] = red[0] + red[1] + red[2] + red[3] + b2[0];
}

// ===========================================================================
extern "C" void kernel_launch(void* const* d_in, const int* in_sizes, int n_in,
                              void* d_out, int out_size, void* d_ws, size_t ws_size,
                              hipStream_t stream)
{
    const int NL = 65536, NP = 131072, EL = 262144, EP = 524288;
    const int B = BGRAPH, H = H_DIM;

    const float* lig_x        = (const float*)d_in[0];
    const float* prot_x       = (const float*)d_in[1];
    const float* lig_embed_W  = (const float*)d_in[2];
    const float* lig_embed_b  = (const float*)d_in[3];
    const float* prot_embed_W = (const float*)d_in[4];
    const float* prot_embed_b = (const float*)d_in[5];
    const float* lig_virtual0 = (const float*)d_in[6];
    const float* prot_virtual0= (const float*)d_in[7];
    const float* lig_conv_W1  = (const float*)d_in[8];
    const float* lig_conv_b1  = (const float*)d_in[9];
    const float* lig_conv_W2  = (const float*)d_in[10];
    const float* lig_conv_b2  = (const float*)d_in[11];
    const float* lig_vmlp_W   = (const float*)d_in[12];
    const float* lig_vmlp_b   = (const float*)d_in[13];
    const float* lig_vmlp_g   = (const float*)d_in[14];
    const float* lig_vmlp_be  = (const float*)d_in[15];
    const float* prot_conv_W1 = (const float*)d_in[16];
    const float* prot_conv_b1 = (const float*)d_in[17];
    const float* prot_conv_W2 = (const float*)d_in[18];
    const float* prot_conv_b2 = (const float*)d_in[19];
    const float* prot_vmlp_W  = (const float*)d_in[20];
    const float* prot_vmlp_b  = (const float*)d_in[21];
    const float* prot_vmlp_g  = (const float*)d_in[22];
    const float* prot_vmlp_be = (const float*)d_in[23];
    const float* pred_W1      = (const float*)d_in[24];
    const float* pred_b1      = (const float*)d_in[25];
    const float* pred_W2      = (const float*)d_in[26];
    const float* pred_b2      = (const float*)d_in[27];
    const int* lig_batch      = (const int*)d_in[28];
    const int* prot_batch     = (const int*)d_in[29];
    const int* lig_ei         = (const int*)d_in[30];
    const int* prot_ei        = (const int*)d_in[31];

    // ---- workspace layout (~225 MB) ----
    float* ws = (float*)d_ws;
    float* lig_v    = ws;                          // B*H
    float* prot_v   = lig_v    + (size_t)B * H;    // B*H
    float* vtmp     = prot_v   + (size_t)B * H;    // B*H
    float* scale    = vtmp     + (size_t)B * H;    // H
    float* shift    = scale    + H;                // H
    float* part     = shift    + H;                // 64*H
    float* comb     = part     + 64 * H;           // B*2H
    float* hidden   = comb     + (size_t)B * 2 * H;// B*H
    float* hsum_lig = hidden   + (size_t)B * H;    // B*H
    float* hsum_prot= hsum_lig + (size_t)B * H;    // B*H
    unsigned short* lig_h0  = (unsigned short*)(hsum_prot + (size_t)B * H);
    unsigned short* lig_h1  = lig_h0  + (size_t)NL * H;
    unsigned short* prot_h0 = lig_h1  + (size_t)NL * H;
    unsigned short* prot_h1 = prot_h0 + (size_t)NP * H;
    unsigned short* wt_lw1  = prot_h1 + (size_t)NP * H;   // 5*H*H each
    unsigned short* wt_lw2  = wt_lw1 + (size_t)NLAYER * H * H;
    unsigned short* wt_pw1  = wt_lw2 + (size_t)NLAYER * H * H;
    unsigned short* wt_pw2  = wt_pw1 + (size_t)NLAYER * H * H;
    int* deg_lig  = (int*)(wt_pw2 + (size_t)NLAYER * H * H); // NL
    int* deg_prot = deg_lig  + NL;                   // NP
    int* bkt_lig  = deg_prot + NP;                   // NL*CAP
    int* bkt_prot = bkt_lig  + (size_t)NL * CAP;     // NP*CAP

    // ---- one-time-per-call prep ----
    hipMemsetAsync(deg_lig, 0, (size_t)(NL + NP) * sizeof(int), stream);
    bucket_build_kernel<<<EL / 256, 256, 0, stream>>>(
        lig_ei, lig_ei + EL, EL, deg_lig, bkt_lig);
    bucket_build_kernel<<<EP / 256, 256, 0, stream>>>(
        prot_ei, prot_ei + EP, EP, deg_prot, bkt_prot);
    wprep_kernel<<<dim3(4, 4, NLAYER), 256, 0, stream>>>(lig_conv_W1, wt_lw1);
    wprep_kernel<<<dim3(4, 4, NLAYER), 256, 0, stream>>>(lig_conv_W2, wt_lw2);
    wprep_kernel<<<dim3(4, 4, NLAYER), 256, 0, stream>>>(prot_conv_W1, wt_pw1);
    wprep_kernel<<<dim3(4, 4, NLAYER), 256, 0, stream>>>(prot_conv_W2, wt_pw2);

    // ---- embeddings ----
    embed_kernel<<<NL / 8, 256, 0, stream>>>(lig_x, lig_embed_W, lig_embed_b, lig_h0, 26);
    embed_kernel<<<NP / 8, 256, 0, stream>>>(prot_x, prot_embed_W, prot_embed_b, prot_h0, 20);
    init_v_kernel<<<B, 256, 0, stream>>>(lig_virtual0, prot_virtual0, lig_v, prot_v);

    auto layer = [&](int i, unsigned short* h_in, unsigned short* h_out,
                     int Nn, int cnt, float* v, float* hsum,
                     const float* vW, const float* vb, const float* vg, const float* vbe,
                     const unsigned short* Wt1, const float* b1,
                     const unsigned short* Wt2, const float* b2,
                     const int* batch, const int* deg, const int* bkt) {
        if (i == 0)
            pool_add_kernel<<<B, 256, 0, stream>>>(h_in, v, cnt);
        else
            v_add_kernel<<<B, 256, 0, stream>>>(v, hsum);
        gemm_small_kernel<false><<<dim3(B / 32, 4), 256, 0, stream>>>(
            v, vW, vb, vtmp, B, H, H);
        bn_part_kernel<<<32, 256, 0, stream>>>(vtmp, part);
        bn_finalize_kernel<<<1, 256, 0, stream>>>(part, vg, vbe, scale, shift);
        bn_relu_kernel<<<B, 256, 0, stream>>>(vtmp, scale, shift, v);
        hipMemsetAsync(hsum, 0, (size_t)B * H * sizeof(float), stream);
        conv_fused2_kernel<<<Nn / 64, 512, 0, stream>>>(
            h_in, deg, bkt, batch, v, Wt1, b1, Wt2, b2, h_out, hsum);
    };

    for (int i = 0; i < NLAYER; ++i) {
        const size_t wo = (size_t)i * H * H;
        const size_t bo = (size_t)i * H;
        unsigned short* lin  = (i & 1) ? lig_h1  : lig_h0;
        unsigned short* lout = (i & 1) ? lig_h0  : lig_h1;
        unsigned short* pin  = (i & 1) ? prot_h1 : prot_h0;
        unsigned short* pout = (i & 1) ? prot_h0 : prot_h1;
        layer(i, lin, lout, NL, 64, lig_v, hsum_lig,
              lig_vmlp_W + wo, lig_vmlp_b + bo, lig_vmlp_g + bo, lig_vmlp_be + bo,
              wt_lw1 + wo, lig_conv_b1 + bo, wt_lw2 + wo, lig_conv_b2 + bo,
              lig_batch, deg_lig, bkt_lig);
        layer(i, pin, pout, NP, 128, prot_v, hsum_prot,
              prot_vmlp_W + wo, prot_vmlp_b + bo, prot_vmlp_g + bo, prot_vmlp_be + bo,
              wt_pw1 + wo, prot_conv_b1 + bo, wt_pw2 + wo, prot_conv_b2 + bo,
              prot_batch, deg_prot, bkt_prot);
    }

    // ---- readout (pools come from last conv's hsum) ----
    pool_hsum_kernel<<<B, 256, 0, stream>>>(hsum_lig, hsum_prot, comb);
    gemm_small_kernel<true><<<dim3(B / 32, 4), 256, 0, stream>>>(
        comb, pred_W1, pred_b1, hidden, B, H, 2 * H);
    pred_final_kernel<<<B, 256, 0, stream>>>(hidden, pred_W2, pred_b2, (float*)d_out);
}

// Round 8
// 1822.714 us; speedup vs baseline: 1.0142x; 1.0142x over previous
//
#include <hip/hip_runtime.h>

#define H_DIM 256
#define NLAYER 5
#define BGRAPH 1024
#define CAP 24

typedef __attribute__((ext_vector_type(8))) short short8;
typedef __attribute__((ext_vector_type(4))) float f32x4;

// ---- bf16 helpers (storage-only; math fp32 / MFMA-fp32-accum) ----
struct __align__(8) us4 { unsigned short x, y, z, w; };

__device__ __forceinline__ float b2f(unsigned short u) {
    union { float f; unsigned v; } c; c.v = ((unsigned)u) << 16; return c.f;
}
__device__ __forceinline__ unsigned short f2b(float f) {
    union { float f; unsigned v; } c; c.f = f;
    return (unsigned short)((c.v + 0x7fffu + ((c.v >> 16) & 1u)) >> 16);
}

// ---------------------------------------------------------------- embed ----
__global__ __launch_bounds__(256) void embed_kernel(
    const float* __restrict__ x, const float* __restrict__ W,
    const float* __restrict__ b, unsigned short* __restrict__ h, int K)
{
    __shared__ float xs[256];            // 8 rows * K (K <= 32)
    const int m0 = blockIdx.x * 8;
    const int tid = threadIdx.x;
    if (tid < 8 * K) xs[tid] = x[(size_t)m0 * K + tid];
    __syncthreads();
    const int n = tid;
    float acc[8] = {0.f,0.f,0.f,0.f,0.f,0.f,0.f,0.f};
    for (int k = 0; k < K; ++k) {
        const float w = W[k * H_DIM + n];
        #pragma unroll
        for (int r = 0; r < 8; ++r) acc[r] += xs[r * K + k] * w;
    }
    const float bb = b[n];
    #pragma unroll
    for (int r = 0; r < 8; ++r)
        h[(size_t)(m0 + r) * H_DIM + n] = f2b(acc[r] + bb);
}

// ---------------------------------------------------------------- init v ---
__global__ __launch_bounds__(256) void init_v_kernel(
    const float* __restrict__ lig0, const float* __restrict__ prot0,
    float* __restrict__ lig_v, float* __restrict__ prot_v)
{
    const int b = blockIdx.x, n = threadIdx.x;
    lig_v[b * H_DIM + n]  = lig0[n];
    prot_v[b * H_DIM + n] = prot0[n];
}

// ---------------------- weight prep: fragment-major bf16 -------------------
// Tile (kb, nb): 32 k x 16 n. Lane l (q=l>>4, l15=l&15) owns 8 shorts:
// element (k = kb*32 + q*8 + e, n = nb*16 + l15).
// Flat: Wf[((kb*16 + nb)*64 + lane)*8 + e]  -> wave fragment load = 1 KB coalesced.
__global__ __launch_bounds__(64) void wprep_kernel(
    const float* __restrict__ W, unsigned short* __restrict__ Wf)
{
    const int kb = blockIdx.x, nb = blockIdx.y, l = blockIdx.z;
    const int lane = threadIdx.x, q = lane >> 4, l15 = lane & 15;
    const float* Wl = W + (size_t)l * 65536;
    unsigned short* dst = Wf + (size_t)l * 65536
                        + ((size_t)(kb * 16 + nb) * 64 + lane) * 8;
    const int kbase = kb * 32 + q * 8;
    const int n = nb * 16 + l15;
    us4 o0, o1;
    o0.x = f2b(Wl[(size_t)(kbase + 0) * 256 + n]);
    o0.y = f2b(Wl[(size_t)(kbase + 1) * 256 + n]);
    o0.z = f2b(Wl[(size_t)(kbase + 2) * 256 + n]);
    o0.w = f2b(Wl[(size_t)(kbase + 3) * 256 + n]);
    o1.x = f2b(Wl[(size_t)(kbase + 4) * 256 + n]);
    o1.y = f2b(Wl[(size_t)(kbase + 5) * 256 + n]);
    o1.z = f2b(Wl[(size_t)(kbase + 6) * 256 + n]);
    o1.w = f2b(Wl[(size_t)(kbase + 7) * 256 + n]);
    *(us4*)dst = o0;
    *(us4*)(dst + 4) = o1;
}

// ------------------------------------------------------- bucket build ------
__global__ __launch_bounds__(256) void bucket_build_kernel(
    const int* __restrict__ src, const int* __restrict__ dst, int E,
    int* __restrict__ deg, int* __restrict__ bucket)
{
    const int e = blockIdx.x * 256 + threadIdx.x;
    if (e >= E) return;
    const int d = dst[e], s = src[e];
    const int slot = atomicAdd(&deg[d], 1);
    if (slot < CAP) bucket[(size_t)d * CAP + slot] = s;
}

// ------------------------------------------------------------ pool0 --------
__global__ __launch_bounds__(256) void pool0_kernel(
    const unsigned short* __restrict__ hL, const unsigned short* __restrict__ hP,
    float* __restrict__ hsL, float* __restrict__ hsP)
{
    const int br = blockIdx.y, b = blockIdx.x, n = threadIdx.x;
    const unsigned short* h = br ? hP : hL;
    float* hs = br ? hsP : hsL;
    const int cnt = br ? 128 : 64;
    const unsigned short* hp = &h[(size_t)b * cnt * H_DIM + n];
    float s = 0.f;
    #pragma unroll 8
    for (int r = 0; r < cnt; ++r) s += b2f(hp[(size_t)r * H_DIM]);
    hs[(size_t)b * H_DIM + n] = s;
}

// ------------------------------------- fused vmlp GEMM + BN stats ----------
// vtmp = (v + hsum) @ W + b ; part[br][0][n] += col sums, [1][n] += col sq-sums
__global__ __launch_bounds__(256) void vmlp_gemm_kernel(
    const float* __restrict__ vL, const float* __restrict__ hsL,
    const float* __restrict__ WL, const float* __restrict__ bL,
    const float* __restrict__ vP, const float* __restrict__ hsP,
    const float* __restrict__ WP, const float* __restrict__ bP,
    float* __restrict__ vtL, float* __restrict__ vtP,
    float* __restrict__ part)
{
    constexpr int BM = 32, BN = 64, BK = 32, TM = 2, K = H_DIM, N = H_DIM;
    __shared__ __align__(16) float As[BK][BM + 4];
    __shared__ __align__(16) float Bs[BK][BN];
    __shared__ float st[2][64];
    const int br = blockIdx.z;
    const float* v    = br ? vP  : vL;
    const float* hsum = br ? hsP : hsL;
    const float* W    = br ? WP  : WL;
    const float* bias = br ? bP  : bL;
    float* vt = br ? vtP : vtL;
    float* pt = part + br * 512;
    const int tid = threadIdx.x;
    const int tx = tid & 15;
    const int ty = tid >> 4;
    const int m0 = blockIdx.x * BM;
    const int n0 = blockIdx.y * BN;

    float acc[TM][4] = {};

    for (int kt = 0; kt < K; kt += BK) {
        {
            const int row = tid >> 3, kq = tid & 7;
            const size_t ao = (size_t)(m0 + row) * K + kt + kq * 4;
            float4 a = *(const float4*)&v[ao];
            const float4 h4 = *(const float4*)&hsum[ao];
            a.x += h4.x; a.y += h4.y; a.z += h4.z; a.w += h4.w;
            As[kq * 4 + 0][row] = a.x;
            As[kq * 4 + 1][row] = a.y;
            As[kq * 4 + 2][row] = a.z;
            As[kq * 4 + 3][row] = a.w;
        }
        #pragma unroll
        for (int i = 0; i < 2; ++i) {
            const int f = tid + i * 256;
            const int row = f >> 4, c4 = f & 15;
            *(float4*)&Bs[row][c4 * 4] =
                *(const float4*)&W[(size_t)(kt + row) * N + n0 + c4 * 4];
        }
        __syncthreads();
        #pragma unroll
        for (int kk = 0; kk < BK; ++kk) {
            const float4 bv = *(const float4*)&Bs[kk][tx * 4];
            #pragma unroll
            for (int im = 0; im < TM; ++im) {
                const float a = As[kk][ty * TM + im];
                acc[im][0] += a * bv.x; acc[im][1] += a * bv.y;
                acc[im][2] += a * bv.z; acc[im][3] += a * bv.w;
            }
        }
        __syncthreads();
    }

    if (tid < 128) ((float*)st)[tid] = 0.f;
    __syncthreads();

    const float4 bb = *(const float4*)&bias[n0 + tx * 4];
    float cs[4] = {0.f,0.f,0.f,0.f}, cq[4] = {0.f,0.f,0.f,0.f};
    #pragma unroll
    for (int im = 0; im < TM; ++im) {
        const int m = m0 + ty * TM + im;
        float4 r;
        r.x = acc[im][0] + bb.x; r.y = acc[im][1] + bb.y;
        r.z = acc[im][2] + bb.z; r.w = acc[im][3] + bb.w;
        *(float4*)&vt[(size_t)m * N + n0 + tx * 4] = r;
        cs[0] += r.x; cq[0] += r.x * r.x;
        cs[1] += r.y; cq[1] += r.y * r.y;
        cs[2] += r.z; cq[2] += r.z * r.z;
        cs[3] += r.w; cq[3] += r.w * r.w;
    }
    #pragma unroll
    for (int c = 0; c < 4; ++c) {
        atomicAdd(&st[0][tx * 4 + c], cs[c]);
        atomicAdd(&st[1][tx * 4 + c], cq[c]);
    }
    __syncthreads();
    if (tid < 64) {
        atomicAdd(&pt[n0 + tid], st[0][tid]);
        atomicAdd(&pt[256 + n0 + tid], st[1][tid]);
    }
}

// ------------------------------------------ BN finalize + relu -> v --------
__global__ __launch_bounds__(256) void vmlp_apply_kernel(
    const float* __restrict__ part,
    const float* __restrict__ gL, const float* __restrict__ beL,
    const float* __restrict__ gP, const float* __restrict__ beP,
    const float* __restrict__ vtL, const float* __restrict__ vtP,
    float* __restrict__ vL, float* __restrict__ vP)
{
    const int br = blockIdx.y, n = threadIdx.x;
    const float* pt = part + br * 512;
    const float* g  = br ? gP  : gL;
    const float* be = br ? beP : beL;
    const float* vt = br ? vtP : vtL;
    float* v = br ? vP : vL;
    const float s  = pt[n];
    const float s2 = pt[256 + n];
    const float mean = s * (1.f / BGRAPH);
    const float var  = s2 * (1.f / BGRAPH) - mean * mean;
    const float sc = g[n] * rsqrtf(var + 1e-5f);
    const float sh = be[n] - mean * sc;
    #pragma unroll
    for (int r = 0; r < 4; ++r) {
        const size_t i = (size_t)(blockIdx.x * 4 + r) * H_DIM + n;
        v[i] = fmaxf(vt[i] * sc + sh, 0.f);
    }
}

// --------------------------------------------- fused gather+conv MFMA ------
// Per 64-row block (rows within one graph):
//   gather z = (Hin[m]+v[g]) + sum_nb (Hin[s]+v[batch[s]]) -> swizzled LDS U
//   GEMM1 t = relu(z@W1+b1) -> U (same swizzled layout);  B direct from L2
//   GEMM2 o = t@W2+b2
//   epilogue Hout = (Hin+v[g]) + o + b2 ; hsum[g] += column sums
// 512 threads = 8 waves (2x4 of 32x64). 4 barriers total, none in K-loops.
__global__ __launch_bounds__(512) void conv_fused3_kernel(
    const unsigned short* __restrict__ Hin,
    const int* __restrict__ deg, const int* __restrict__ bucket,
    const int* __restrict__ batch, const float* __restrict__ v,
    const unsigned short* __restrict__ Wf1, const float* __restrict__ b1,
    const unsigned short* __restrict__ Wf2, const float* __restrict__ b2,
    unsigned short* __restrict__ Hout, float* __restrict__ hsum)
{
    __shared__ __align__(16) unsigned short U[64 * 256];   // 32 KB, swizzled
    __shared__ float hl[256];
    char* Ub = (char*)U;
    const int tid  = threadIdx.x;
    const int lane = tid & 63;
    const int wid  = tid >> 6;
    const int wr   = wid >> 2;
    const int wc   = wid & 3;
    const int q    = lane >> 4;
    const int l15  = lane & 15;
    const int m0   = blockIdx.x * 64;
    const int bq0  = batch[m0];                 // whole block = one graph
    const float* __restrict__ vg = v + (size_t)bq0 * H_DIM;

    if (tid < 256) hl[tid] = 0.f;

    // ---------------- gather ----------------
    {
        const float4 vm = *(const float4*)&vg[lane * 4];
        for (int r8 = 0; r8 < 8; ++r8) {
            const int lr = wid * 8 + r8;
            const int m = m0 + lr;
            const us4 hv = *(const us4*)&Hin[(size_t)m * H_DIM + lane * 4];
            float4 acc = { b2f(hv.x) + vm.x, b2f(hv.y) + vm.y,
                           b2f(hv.z) + vm.z, b2f(hv.w) + vm.w };
            int cnt = deg[m]; if (cnt > CAP) cnt = CAP;
            const int* bp = &bucket[(size_t)m * CAP];
            for (int i = 0; i < cnt; i += 4) {
                const int4 s4 = *(const int4*)&bp[i];
                const int rem = cnt - i;
                us4 a0, a1, a2, a3;
                int q0, q1, q2, q3;
                a0 = *(const us4*)&Hin[(size_t)s4.x * H_DIM + lane * 4];
                q0 = batch[s4.x];
                if (rem > 1) { a1 = *(const us4*)&Hin[(size_t)s4.y * H_DIM + lane * 4]; q1 = batch[s4.y]; }
                if (rem > 2) { a2 = *(const us4*)&Hin[(size_t)s4.z * H_DIM + lane * 4]; q2 = batch[s4.z]; }
                if (rem > 3) { a3 = *(const us4*)&Hin[(size_t)s4.w * H_DIM + lane * 4]; q3 = batch[s4.w]; }
                {
                    const float4 w0 = *(const float4*)&v[(size_t)q0 * H_DIM + lane * 4];
                    acc.x += b2f(a0.x) + w0.x; acc.y += b2f(a0.y) + w0.y;
                    acc.z += b2f(a0.z) + w0.z; acc.w += b2f(a0.w) + w0.w;
                }
                if (rem > 1) {
                    const float4 w1 = *(const float4*)&v[(size_t)q1 * H_DIM + lane * 4];
                    acc.x += b2f(a1.x) + w1.x; acc.y += b2f(a1.y) + w1.y;
                    acc.z += b2f(a1.z) + w1.z; acc.w += b2f(a1.w) + w1.w;
                }
                if (rem > 2) {
                    const float4 w2 = *(const float4*)&v[(size_t)q2 * H_DIM + lane * 4];
                    acc.x += b2f(a2.x) + w2.x; acc.y += b2f(a2.y) + w2.y;
                    acc.z += b2f(a2.z) + w2.z; acc.w += b2f(a2.w) + w2.w;
                }
                if (rem > 3) {
                    const float4 w3 = *(const float4*)&v[(size_t)q3 * H_DIM + lane * 4];
                    acc.x += b2f(a3.x) + w3.x; acc.y += b2f(a3.y) + w3.y;
                    acc.z += b2f(a3.z) + w3.z; acc.w += b2f(a3.w) + w3.w;
                }
            }
            us4 o = { f2b(acc.x), f2b(acc.y), f2b(acc.z), f2b(acc.w) };
            const int ab = lr * 512 + ((lane * 8) ^ ((lr & 7) << 4));
            *(us4*)(Ub + ab) = o;
        }
    }
    __syncthreads();

    f32x4 acc[2][4];
    #pragma unroll
    for (int i = 0; i < 2; ++i)
        #pragma unroll
        for (int j = 0; j < 4; ++j) acc[i][j] = (f32x4){0.f, 0.f, 0.f, 0.f};

    // A-fragment addressing (shared by both GEMMs)
    const int arow = wr * 32 + l15;
    const int rowb0 = arow * 512;
    const int rowb1 = rowb0 + 16 * 512;
    const int xorv = (l15 & 7) << 4;
    // B-fragment base: lane-contiguous fragment tiles in L2
    const unsigned short* wb1 = Wf1 + ((size_t)(wc * 4) * 64 + lane) * 8;
    const unsigned short* wb2 = Wf2 + ((size_t)(wc * 4) * 64 + lane) * 8;

    // ---------------- GEMM1 (no barriers) ----------------
    #pragma unroll 2
    for (int kb = 0; kb < 8; ++kb) {
        const int c0 = (kb * 64 + q * 16) ^ xorv;
        const short8 av0 = *(const short8*)(Ub + rowb0 + c0);
        const short8 av1 = *(const short8*)(Ub + rowb1 + c0);
        #pragma unroll
        for (int ni = 0; ni < 4; ++ni) {
            const short8 bv = *(const short8*)&wb1[(size_t)kb * 8192 + ni * 512];
            acc[0][ni] = __builtin_amdgcn_mfma_f32_16x16x32_bf16(av0, bv, acc[0][ni], 0, 0, 0);
            acc[1][ni] = __builtin_amdgcn_mfma_f32_16x16x32_bf16(av1, bv, acc[1][ni], 0, 0, 0);
        }
    }
    __syncthreads();   // all waves done reading z from U

    // bias + relu -> U (same swizzled layout)
    #pragma unroll
    for (int ni = 0; ni < 4; ++ni) {
        const int col = wc * 64 + ni * 16 + l15;
        const float bb = b1[col];
        #pragma unroll
        for (int mi = 0; mi < 2; ++mi)
            #pragma unroll
            for (int j = 0; j < 4; ++j) {
                const int row = wr * 32 + mi * 16 + q * 4 + j;
                const int tb = row * 512 + ((col * 2) ^ ((row & 7) << 4));
                *(unsigned short*)(Ub + tb) = f2b(fmaxf(acc[mi][ni][j] + bb, 0.f));
            }
    }
    #pragma unroll
    for (int i = 0; i < 2; ++i)
        #pragma unroll
        for (int j = 0; j < 4; ++j) acc[i][j] = (f32x4){0.f, 0.f, 0.f, 0.f};
    __syncthreads();

    // ---------------- GEMM2 (no barriers) ----------------
    #pragma unroll 2
    for (int kb = 0; kb < 8; ++kb) {
        const int c0 = (kb * 64 + q * 16) ^ xorv;
        const short8 av0 = *(const short8*)(Ub + rowb0 + c0);
        const short8 av1 = *(const short8*)(Ub + rowb1 + c0);
        #pragma unroll
        for (int ni = 0; ni < 4; ++ni) {
            const short8 bv = *(const short8*)&wb2[(size_t)kb * 8192 + ni * 512];
            acc[0][ni] = __builtin_amdgcn_mfma_f32_16x16x32_bf16(av0, bv, acc[0][ni], 0, 0, 0);
            acc[1][ni] = __builtin_amdgcn_mfma_f32_16x16x32_bf16(av1, bv, acc[1][ni], 0, 0, 0);
        }
    }

    // ---------------- epilogue: Hout + pooled column sums ----------------
    int cols[4]; float b2c[4], vc[4];
    #pragma unroll
    for (int ni = 0; ni < 4; ++ni) {
        cols[ni] = wc * 64 + ni * 16 + l15;
        b2c[ni] = b2[cols[ni]];
        vc[ni]  = vg[cols[ni]];
    }
    float lsum[4] = {0.f, 0.f, 0.f, 0.f};
    #pragma unroll
    for (int mi = 0; mi < 2; ++mi)
        #pragma unroll
        for (int j = 0; j < 4; ++j) {
            const int row = m0 + wr * 32 + mi * 16 + q * 4 + j;
            const unsigned short* hip_ = &Hin[(size_t)row * H_DIM];
            unsigned short* hop = &Hout[(size_t)row * H_DIM];
            #pragma unroll
            for (int ni = 0; ni < 4; ++ni) {
                const float val = b2f(hip_[cols[ni]]) + vc[ni]
                                + acc[mi][ni][j] + b2c[ni];
                hop[cols[ni]] = f2b(val);
                lsum[ni] += val;
            }
        }
    #pragma unroll
    for (int ni = 0; ni < 4; ++ni) atomicAdd(&hl[cols[ni]], lsum[ni]);
    __syncthreads();
    if (tid < 256) atomicAdd(&hsum[(size_t)bq0 * H_DIM + tid], hl[tid]);
}

// ----------------------------------------------------- small fp32 GEMM -----
template<bool RELU>
__global__ __launch_bounds__(256) void gemm_small_kernel(
    const float* __restrict__ A, const float* __restrict__ W,
    const float* __restrict__ bias, float* __restrict__ C,
    int M, int N, int K)
{
    constexpr int BM = 32, BN = 64, BK = 32, TM = 2;
    __shared__ __align__(16) float As[BK][BM + 4];
    __shared__ __align__(16) float Bs[BK][BN];
    const int tid = threadIdx.x;
    const int tx = tid & 15;
    const int ty = tid >> 4;
    const int m0 = blockIdx.x * BM;
    const int n0 = blockIdx.y * BN;

    float acc[TM][4] = {};

    for (int kt = 0; kt < K; kt += BK) {
        {
            const int row = tid >> 3, kq = tid & 7;
            const float4 a = *(const float4*)&A[(size_t)(m0 + row) * K + kt + kq * 4];
            As[kq * 4 + 0][row] = a.x;
            As[kq * 4 + 1][row] = a.y;
            As[kq * 4 + 2][row] = a.z;
            As[kq * 4 + 3][row] = a.w;
        }
        #pragma unroll
        for (int i = 0; i < 2; ++i) {
            const int f = tid + i * 256;
            const int row = f >> 4, c4 = f & 15;
            *(float4*)&Bs[row][c4 * 4] =
                *(const float4*)&W[(size_t)(kt + row) * N + n0 + c4 * 4];
        }
        __syncthreads();
        #pragma unroll
        for (int kk = 0; kk < BK; ++kk) {
            const float4 bv = *(const float4*)&Bs[kk][tx * 4];
            #pragma unroll
            for (int im = 0; im < TM; ++im) {
                const float a = As[kk][ty * TM + im];
                acc[im][0] += a * bv.x; acc[im][1] += a * bv.y;
                acc[im][2] += a * bv.z; acc[im][3] += a * bv.w;
            }
        }
        __syncthreads();
    }

    const float4 bb = *(const float4*)&bias[n0 + tx * 4];
    #pragma unroll
    for (int im = 0; im < TM; ++im) {
        const int m = m0 + ty * TM + im;
        float4 r;
        r.x = acc[im][0] + bb.x; r.y = acc[im][1] + bb.y;
        r.z = acc[im][2] + bb.z; r.w = acc[im][3] + bb.w;
        if constexpr (RELU) {
            r.x = fmaxf(r.x, 0.f); r.y = fmaxf(r.y, 0.f);
            r.z = fmaxf(r.z, 0.f); r.w = fmaxf(r.w, 0.f);
        }
        *(float4*)&C[(size_t)m * N + n0 + tx * 4] = r;
    }
}

// ------------------------------------------------- readout from hsum -------
__global__ __launch_bounds__(256) void pool_hsum_kernel(
    const float* __restrict__ hl, const float* __restrict__ hp,
    float* __restrict__ comb)
{
    const int b = blockIdx.x, n = threadIdx.x;
    comb[(size_t)b * 512 + n]       = hl[(size_t)b * H_DIM + n] * (1.f / 64.f);
    comb[(size_t)b * 512 + 256 + n] = hp[(size_t)b * H_DIM + n] * (1.f / 128.f);
}

// ------------------------------------------------------------ final dot ----
__global__ __launch_bounds__(256) void pred_final_kernel(
    const float* __restrict__ hidden, const float* __restrict__ W2,
    const float* __restrict__ b2, float* __restrict__ out)
{
    const int b = blockIdx.x, t = threadIdx.x;
    float p = hidden[(size_t)b * H_DIM + t] * W2[t];
    #pragma unroll
    for (int off = 32; off >= 1; off >>= 1) p += __shfl_down(p, off);
    __shared__ float red[4];
    if ((t & 63) == 0) red[t >> 6] = p;
    __syncthreads();
    if (t == 0) out[b] = red[0] + red[1] + red[2] + red[3] + b2[0];
}

// ===========================================================================
extern "C" void kernel_launch(void* const* d_in, const int* in_sizes, int n_in,
                              void* d_out, int out_size, void* d_ws, size_t ws_size,
                              hipStream_t stream)
{
    const int NL = 65536, NP = 131072, EL = 262144, EP = 524288;
    const int B = BGRAPH, H = H_DIM;

    const float* lig_x        = (const float*)d_in[0];
    const float* prot_x       = (const float*)d_in[1];
    const float* lig_embed_W  = (const float*)d_in[2];
    const float* lig_embed_b  = (const float*)d_in[3];
    const float* prot_embed_W = (const float*)d_in[4];
    const float* prot_embed_b = (const float*)d_in[5];
    const float* lig_virtual0 = (const float*)d_in[6];
    const float* prot_virtual0= (const float*)d_in[7];
    const float* lig_conv_W1  = (const float*)d_in[8];
    const float* lig_conv_b1  = (const float*)d_in[9];
    const float* lig_conv_W2  = (const float*)d_in[10];
    const float* lig_conv_b2  = (const float*)d_in[11];
    const float* lig_vmlp_W   = (const float*)d_in[12];
    const float* lig_vmlp_b   = (const float*)d_in[13];
    const float* lig_vmlp_g   = (const float*)d_in[14];
    const float* lig_vmlp_be  = (const float*)d_in[15];
    const float* prot_conv_W1 = (const float*)d_in[16];
    const float* prot_conv_b1 = (const float*)d_in[17];
    const float* prot_conv_W2 = (const float*)d_in[18];
    const float* prot_conv_b2 = (const float*)d_in[19];
    const float* prot_vmlp_W  = (const float*)d_in[20];
    const float* prot_vmlp_b  = (const float*)d_in[21];
    const float* prot_vmlp_g  = (const float*)d_in[22];
    const float* prot_vmlp_be = (const float*)d_in[23];
    const float* pred_W1      = (const float*)d_in[24];
    const float* pred_b1      = (const float*)d_in[25];
    const float* pred_W2      = (const float*)d_in[26];
    const float* pred_b2      = (const float*)d_in[27];
    const int* lig_batch      = (const int*)d_in[28];
    const int* prot_batch     = (const int*)d_in[29];
    const int* lig_ei         = (const int*)d_in[30];
    const int* prot_ei        = (const int*)d_in[31];

    // ---- workspace layout (~233 MB) ----
    float* ws = (float*)d_ws;
    float* lig_v    = ws;                          // B*H
    float* prot_v   = lig_v    + (size_t)B * H;    // B*H
    float* vtmpL    = prot_v   + (size_t)B * H;    // B*H
    float* vtmpP    = vtmpL    + (size_t)B * H;    // B*H
    float* part     = vtmpP    + (size_t)B * H;    // 2*2*256 = 1024
    float* comb     = part     + 1024;             // B*2H
    float* hidden   = comb     + (size_t)B * 2 * H;// B*H
    float* hsum_lig = hidden   + (size_t)B * H;    // B*H  (contiguous with
    float* hsum_prot= hsum_lig + (size_t)B * H;    //  hsum_prot for 1 memset)
    unsigned short* lig_h0  = (unsigned short*)(hsum_prot + (size_t)B * H);
    unsigned short* lig_h1  = lig_h0  + (size_t)NL * H;
    unsigned short* prot_h0 = lig_h1  + (size_t)NL * H;
    unsigned short* prot_h1 = prot_h0 + (size_t)NP * H;
    unsigned short* wf_lw1  = prot_h1 + (size_t)NP * H;   // 5*H*H each
    unsigned short* wf_lw2  = wf_lw1 + (size_t)NLAYER * H * H;
    unsigned short* wf_pw1  = wf_lw2 + (size_t)NLAYER * H * H;
    unsigned short* wf_pw2  = wf_pw1 + (size_t)NLAYER * H * H;
    int* deg_lig  = (int*)(wf_pw2 + (size_t)NLAYER * H * H); // NL
    int* deg_prot = deg_lig  + NL;                   // NP
    int* bkt_lig  = deg_prot + NP;                   // NL*CAP
    int* bkt_prot = bkt_lig  + (size_t)NL * CAP;     // NP*CAP

    // ---- one-time-per-call prep ----
    hipMemsetAsync(deg_lig, 0, (size_t)(NL + NP) * sizeof(int), stream);
    bucket_build_kernel<<<EL / 256, 256, 0, stream>>>(
        lig_ei, lig_ei + EL, EL, deg_lig, bkt_lig);
    bucket_build_kernel<<<EP / 256, 256, 0, stream>>>(
        prot_ei, prot_ei + EP, EP, deg_prot, bkt_prot);
    wprep_kernel<<<dim3(8, 16, NLAYER), 64, 0, stream>>>(lig_conv_W1, wf_lw1);
    wprep_kernel<<<dim3(8, 16, NLAYER), 64, 0, stream>>>(lig_conv_W2, wf_lw2);
    wprep_kernel<<<dim3(8, 16, NLAYER), 64, 0, stream>>>(prot_conv_W1, wf_pw1);
    wprep_kernel<<<dim3(8, 16, NLAYER), 64, 0, stream>>>(prot_conv_W2, wf_pw2);

    // ---- embeddings + pool0 ----
    embed_kernel<<<NL / 8, 256, 0, stream>>>(lig_x, lig_embed_W, lig_embed_b, lig_h0, 26);
    embed_kernel<<<NP / 8, 256, 0, stream>>>(prot_x, prot_embed_W, prot_embed_b, prot_h0, 20);
    init_v_kernel<<<B, 256, 0, stream>>>(lig_virtual0, prot_virtual0, lig_v, prot_v);
    pool0_kernel<<<dim3(B, 2), 256, 0, stream>>>(lig_h0, prot_h0, hsum_lig, hsum_prot);

    for (int i = 0; i < NLAYER; ++i) {
        const size_t wo = (size_t)i * H * H;
        const size_t bo = (size_t)i * H;
        unsigned short* lin  = (i & 1) ? lig_h1  : lig_h0;
        unsigned short* lout = (i & 1) ? lig_h0  : lig_h1;
        unsigned short* pin  = (i & 1) ? prot_h1 : prot_h0;
        unsigned short* pout = (i & 1) ? prot_h0 : prot_h1;

        hipMemsetAsync(part, 0, 1024 * sizeof(float), stream);
        vmlp_gemm_kernel<<<dim3(32, 4, 2), 256, 0, stream>>>(
            lig_v, hsum_lig, lig_vmlp_W + wo, lig_vmlp_b + bo,
            prot_v, hsum_prot, prot_vmlp_W + wo, prot_vmlp_b + bo,
            vtmpL, vtmpP, part);
        vmlp_apply_kernel<<<dim3(256, 2), 256, 0, stream>>>(
            part, lig_vmlp_g + bo, lig_vmlp_be + bo,
            prot_vmlp_g + bo, prot_vmlp_be + bo,
            vtmpL, vtmpP, lig_v, prot_v);
        hipMemsetAsync(hsum_lig, 0, (size_t)2 * B * H * sizeof(float), stream);
        conv_fused3_kernel<<<NL / 64, 512, 0, stream>>>(
            lin, deg_lig, bkt_lig, lig_batch, lig_v,
            wf_lw1 + wo, lig_conv_b1 + bo, wf_lw2 + wo, lig_conv_b2 + bo,
            lout, hsum_lig);
        conv_fused3_kernel<<<NP / 64, 512, 0, stream>>>(
            pin, deg_prot, bkt_prot, prot_batch, prot_v,
            wf_pw1 + wo, prot_conv_b1 + bo, wf_pw2 + wo, prot_conv_b2 + bo,
            pout, hsum_prot);
    }

    // ---- readout ----
    pool_hsum_kernel<<<B, 256, 0, stream>>>(hsum_lig, hsum_prot, comb);
    gemm_small_kernel<true><<<dim3(B / 32, 4), 256, 0, stream>>>(
        comb, pred_W1, pred_b1, hidden, B, H, 2 * H);
    pred_final_kernel<<<B, 256, 0, stream>>>(hidden, pred_W2, pred_b2, (float*)d_out);
}

// Round 9
// 1754.584 us; speedup vs baseline: 1.0536x; 1.0388x over previous
//
#include <hip/hip_runtime.h>

#define H_DIM 256
#define NLAYER 5
#define BGRAPH 1024
#define CAP 24

typedef __attribute__((ext_vector_type(8))) short short8;
typedef __attribute__((ext_vector_type(4))) float f32x4;

// ---- bf16 helpers (storage-only; math fp32 / MFMA-fp32-accum) ----
struct __align__(8) us4 { unsigned short x, y, z, w; };

__device__ __forceinline__ float b2f(unsigned short u) {
    union { float f; unsigned v; } c; c.v = ((unsigned)u) << 16; return c.f;
}
__device__ __forceinline__ unsigned short f2b(float f) {
    union { float f; unsigned v; } c; c.f = f;
    return (unsigned short)((c.v + 0x7fffu + ((c.v >> 16) & 1u)) >> 16);
}

// ---------------------------------------------------------------- embed ----
__global__ __launch_bounds__(256) void embed_kernel(
    const float* __restrict__ x, const float* __restrict__ W,
    const float* __restrict__ b, unsigned short* __restrict__ h, int K)
{
    __shared__ float xs[256];            // 8 rows * K (K <= 32)
    const int m0 = blockIdx.x * 8;
    const int tid = threadIdx.x;
    if (tid < 8 * K) xs[tid] = x[(size_t)m0 * K + tid];
    __syncthreads();
    const int n = tid;
    float acc[8] = {0.f,0.f,0.f,0.f,0.f,0.f,0.f,0.f};
    for (int k = 0; k < K; ++k) {
        const float w = W[k * H_DIM + n];
        #pragma unroll
        for (int r = 0; r < 8; ++r) acc[r] += xs[r * K + k] * w;
    }
    const float bb = b[n];
    #pragma unroll
    for (int r = 0; r < 8; ++r)
        h[(size_t)(m0 + r) * H_DIM + n] = f2b(acc[r] + bb);
}

// ---------------------------------------------------------------- init v ---
__global__ __launch_bounds__(256) void init_v_kernel(
    const float* __restrict__ lig0, const float* __restrict__ prot0,
    float* __restrict__ lig_v, float* __restrict__ prot_v)
{
    const int b = blockIdx.x, n = threadIdx.x;
    lig_v[b * H_DIM + n]  = lig0[n];
    prot_v[b * H_DIM + n] = prot0[n];
}

// ---------------------- weight prep: fragment-major bf16 -------------------
// Tile (kb, nb): 32 k x 16 n. Lane l (q=l>>4, l15=l&15) owns 8 shorts:
// element (k = kb*32 + q*8 + e, n = nb*16 + l15).
// Flat: Wf[((kb*16 + nb)*64 + lane)*8 + e]  -> wave fragment load = 1 KB coalesced.
__global__ __launch_bounds__(64) void wprep_kernel(
    const float* __restrict__ W, unsigned short* __restrict__ Wf)
{
    const int kb = blockIdx.x, nb = blockIdx.y, l = blockIdx.z;
    const int lane = threadIdx.x, q = lane >> 4, l15 = lane & 15;
    const float* Wl = W + (size_t)l * 65536;
    unsigned short* dst = Wf + (size_t)l * 65536
                        + ((size_t)(kb * 16 + nb) * 64 + lane) * 8;
    const int kbase = kb * 32 + q * 8;
    const int n = nb * 16 + l15;
    us4 o0, o1;
    o0.x = f2b(Wl[(size_t)(kbase + 0) * 256 + n]);
    o0.y = f2b(Wl[(size_t)(kbase + 1) * 256 + n]);
    o0.z = f2b(Wl[(size_t)(kbase + 2) * 256 + n]);
    o0.w = f2b(Wl[(size_t)(kbase + 3) * 256 + n]);
    o1.x = f2b(Wl[(size_t)(kbase + 4) * 256 + n]);
    o1.y = f2b(Wl[(size_t)(kbase + 5) * 256 + n]);
    o1.z = f2b(Wl[(size_t)(kbase + 6) * 256 + n]);
    o1.w = f2b(Wl[(size_t)(kbase + 7) * 256 + n]);
    *(us4*)dst = o0;
    *(us4*)(dst + 4) = o1;
}

// ------------------------------------------------------- bucket build ------
__global__ __launch_bounds__(256) void bucket_build_kernel(
    const int* __restrict__ src, const int* __restrict__ dst, int E,
    int* __restrict__ deg, int* __restrict__ bucket)
{
    const int e = blockIdx.x * 256 + threadIdx.x;
    if (e >= E) return;
    const int d = dst[e], s = src[e];
    const int slot = atomicAdd(&deg[d], 1);
    if (slot < CAP) bucket[(size_t)d * CAP + slot] = s;
}

// ------------------------------------------------------------ pool0 --------
__global__ __launch_bounds__(256) void pool0_kernel(
    const unsigned short* __restrict__ hL, const unsigned short* __restrict__ hP,
    float* __restrict__ hsL, float* __restrict__ hsP)
{
    const int br = blockIdx.y, b = blockIdx.x, n = threadIdx.x;
    const unsigned short* h = br ? hP : hL;
    float* hs = br ? hsP : hsL;
    const int cnt = br ? 128 : 64;
    const unsigned short* hp = &h[(size_t)b * cnt * H_DIM + n];
    float s = 0.f;
    #pragma unroll 8
    for (int r = 0; r < cnt; ++r) s += b2f(hp[(size_t)r * H_DIM]);
    hs[(size_t)b * H_DIM + n] = s;
}

// ------------------------------------- fused vmlp GEMM + BN stats ----------
// vtmp = (v + hsum) @ W + b ; part[br][0][n] += col sums, [1][n] += col sq-sums
__global__ __launch_bounds__(256) void vmlp_gemm_kernel(
    const float* __restrict__ vL, const float* __restrict__ hsL,
    const float* __restrict__ WL, const float* __restrict__ bL,
    const float* __restrict__ vP, const float* __restrict__ hsP,
    const float* __restrict__ WP, const float* __restrict__ bP,
    float* __restrict__ vtL, float* __restrict__ vtP,
    float* __restrict__ part)
{
    constexpr int BM = 32, BN = 64, BK = 32, TM = 2, K = H_DIM, N = H_DIM;
    __shared__ __align__(16) float As[BK][BM + 4];
    __shared__ __align__(16) float Bs[BK][BN];
    __shared__ float st[2][64];
    const int br = blockIdx.z;
    const float* v    = br ? vP  : vL;
    const float* hsum = br ? hsP : hsL;
    const float* W    = br ? WP  : WL;
    const float* bias = br ? bP  : bL;
    float* vt = br ? vtP : vtL;
    float* pt = part + br * 512;
    const int tid = threadIdx.x;
    const int tx = tid & 15;
    const int ty = tid >> 4;
    const int m0 = blockIdx.x * BM;
    const int n0 = blockIdx.y * BN;

    float acc[TM][4] = {};

    for (int kt = 0; kt < K; kt += BK) {
        {
            const int row = tid >> 3, kq = tid & 7;
            const size_t ao = (size_t)(m0 + row) * K + kt + kq * 4;
            float4 a = *(const float4*)&v[ao];
            const float4 h4 = *(const float4*)&hsum[ao];
            a.x += h4.x; a.y += h4.y; a.z += h4.z; a.w += h4.w;
            As[kq * 4 + 0][row] = a.x;
            As[kq * 4 + 1][row] = a.y;
            As[kq * 4 + 2][row] = a.z;
            As[kq * 4 + 3][row] = a.w;
        }
        #pragma unroll
        for (int i = 0; i < 2; ++i) {
            const int f = tid + i * 256;
            const int row = f >> 4, c4 = f & 15;
            *(float4*)&Bs[row][c4 * 4] =
                *(const float4*)&W[(size_t)(kt + row) * N + n0 + c4 * 4];
        }
        __syncthreads();
        #pragma unroll
        for (int kk = 0; kk < BK; ++kk) {
            const float4 bv = *(const float4*)&Bs[kk][tx * 4];
            #pragma unroll
            for (int im = 0; im < TM; ++im) {
                const float a = As[kk][ty * TM + im];
                acc[im][0] += a * bv.x; acc[im][1] += a * bv.y;
                acc[im][2] += a * bv.z; acc[im][3] += a * bv.w;
            }
        }
        __syncthreads();
    }

    if (tid < 128) ((float*)st)[tid] = 0.f;
    __syncthreads();

    const float4 bb = *(const float4*)&bias[n0 + tx * 4];
    float cs[4] = {0.f,0.f,0.f,0.f}, cq[4] = {0.f,0.f,0.f,0.f};
    #pragma unroll
    for (int im = 0; im < TM; ++im) {
        const int m = m0 + ty * TM + im;
        float4 r;
        r.x = acc[im][0] + bb.x; r.y = acc[im][1] + bb.y;
        r.z = acc[im][2] + bb.z; r.w = acc[im][3] + bb.w;
        *(float4*)&vt[(size_t)m * N + n0 + tx * 4] = r;
        cs[0] += r.x; cq[0] += r.x * r.x;
        cs[1] += r.y; cq[1] += r.y * r.y;
        cs[2] += r.z; cq[2] += r.z * r.z;
        cs[3] += r.w; cq[3] += r.w * r.w;
    }
    #pragma unroll
    for (int c = 0; c < 4; ++c) {
        atomicAdd(&st[0][tx * 4 + c], cs[c]);
        atomicAdd(&st[1][tx * 4 + c], cq[c]);
    }
    __syncthreads();
    if (tid < 64) {
        atomicAdd(&pt[n0 + tid], st[0][tid]);
        atomicAdd(&pt[256 + n0 + tid], st[1][tid]);
    }
}

// ------------------------------------------ BN finalize + relu -> v --------
__global__ __launch_bounds__(256) void vmlp_apply_kernel(
    const float* __restrict__ part,
    const float* __restrict__ gL, const float* __restrict__ beL,
    const float* __restrict__ gP, const float* __restrict__ beP,
    const float* __restrict__ vtL, const float* __restrict__ vtP,
    float* __restrict__ vL, float* __restrict__ vP)
{
    const int br = blockIdx.y, n = threadIdx.x;
    const float* pt = part + br * 512;
    const float* g  = br ? gP  : gL;
    const float* be = br ? beP : beL;
    const float* vt = br ? vtP : vtL;
    float* v = br ? vP : vL;
    const float s  = pt[n];
    const float s2 = pt[256 + n];
    const float mean = s * (1.f / BGRAPH);
    const float var  = s2 * (1.f / BGRAPH) - mean * mean;
    const float sc = g[n] * rsqrtf(var + 1e-5f);
    const float sh = be[n] - mean * sc;
    #pragma unroll
    for (int r = 0; r < 4; ++r) {
        const size_t i = (size_t)(blockIdx.x * 4 + r) * H_DIM + n;
        v[i] = fmaxf(vt[i] * sc + sh, 0.f);
    }
}

// --------------------------------------------- fused gather+conv MFMA ------
// 32-row tile, 256 threads = 4 waves (each 32 rows x 64 cols).
// Small tile + pairwise-row gather maximize gather-load concurrency
// (8 blocks/CU, 8 h-row loads in flight per lane).
//   gather z = (Hin[m]+v[g]) + sum_nb (Hin[s]+v[batch[s]]) -> swizzled LDS U
//   GEMM1 t = relu(z@W1+b1) -> U; B fragment-major direct from L2
//   GEMM2 o = t@W2+b2
//   epilogue Hout = (Hin+v[g]) + o + b2 ; hsum[g] += column sums
__global__ __launch_bounds__(256) void conv_fused4_kernel(
    const unsigned short* __restrict__ Hin,
    const int* __restrict__ deg, const int* __restrict__ bucket,
    const int* __restrict__ batch, const float* __restrict__ v,
    const unsigned short* __restrict__ Wf1, const float* __restrict__ b1,
    const unsigned short* __restrict__ Wf2, const float* __restrict__ b2,
    unsigned short* __restrict__ Hout, float* __restrict__ hsum)
{
    __shared__ __align__(16) unsigned short U[32 * 256];   // 16 KB, swizzled
    __shared__ float hl[256];
    char* Ub = (char*)U;
    const int tid  = threadIdx.x;
    const int lane = tid & 63;
    const int wid  = tid >> 6;      // 0..3
    const int wc   = wid;           // column quarter
    const int q    = lane >> 4;
    const int l15  = lane & 15;
    const int m0   = blockIdx.x * 32;
    const int bq0  = batch[m0];                 // whole block = one graph
    const float* __restrict__ vg = v + (size_t)bq0 * H_DIM;

    hl[tid] = 0.f;

    // ---------------- gather (pairwise rows for ILP) ----------------
    {
        const float4 vm = *(const float4*)&vg[lane * 4];
        for (int rp = 0; rp < 8; rp += 2) {
            const int lrA = wid * 8 + rp, lrB = lrA + 1;
            const int mA = m0 + lrA, mB = m0 + lrB;
            const us4 hA = *(const us4*)&Hin[(size_t)mA * H_DIM + lane * 4];
            const us4 hB = *(const us4*)&Hin[(size_t)mB * H_DIM + lane * 4];
            int cntA = deg[mA]; if (cntA > CAP) cntA = CAP;
            int cntB = deg[mB]; if (cntB > CAP) cntB = CAP;
            const int* bpA = &bucket[(size_t)mA * CAP];
            const int* bpB = &bucket[(size_t)mB * CAP];
            float4 aA = { b2f(hA.x) + vm.x, b2f(hA.y) + vm.y,
                          b2f(hA.z) + vm.z, b2f(hA.w) + vm.w };
            float4 aB = { b2f(hB.x) + vm.x, b2f(hB.y) + vm.y,
                          b2f(hB.z) + vm.z, b2f(hB.w) + vm.w };
            const int cmax = cntA > cntB ? cntA : cntB;
            for (int i = 0; i < cmax; i += 4) {
                us4 xa0, xa1, xa2, xa3, xb0, xb1, xb2, xb3;
                int qa0, qa1, qa2, qa3, qb0, qb1, qb2, qb3;
                int remA = cntA - i, remB = cntB - i;
                int4 sA, sB;
                if (remA > 0) {
                    sA = *(const int4*)&bpA[i];
                    xa0 = *(const us4*)&Hin[(size_t)sA.x * H_DIM + lane * 4]; qa0 = batch[sA.x];
                    if (remA > 1) { xa1 = *(const us4*)&Hin[(size_t)sA.y * H_DIM + lane * 4]; qa1 = batch[sA.y]; }
                    if (remA > 2) { xa2 = *(const us4*)&Hin[(size_t)sA.z * H_DIM + lane * 4]; qa2 = batch[sA.z]; }
                    if (remA > 3) { xa3 = *(const us4*)&Hin[(size_t)sA.w * H_DIM + lane * 4]; qa3 = batch[sA.w]; }
                }
                if (remB > 0) {
                    sB = *(const int4*)&bpB[i];
                    xb0 = *(const us4*)&Hin[(size_t)sB.x * H_DIM + lane * 4]; qb0 = batch[sB.x];
                    if (remB > 1) { xb1 = *(const us4*)&Hin[(size_t)sB.y * H_DIM + lane * 4]; qb1 = batch[sB.y]; }
                    if (remB > 2) { xb2 = *(const us4*)&Hin[(size_t)sB.z * H_DIM + lane * 4]; qb2 = batch[sB.z]; }
                    if (remB > 3) { xb3 = *(const us4*)&Hin[(size_t)sB.w * H_DIM + lane * 4]; qb3 = batch[sB.w]; }
                }
                if (remA > 0) {
                    const float4 w = *(const float4*)&v[(size_t)qa0 * H_DIM + lane * 4];
                    aA.x += b2f(xa0.x) + w.x; aA.y += b2f(xa0.y) + w.y;
                    aA.z += b2f(xa0.z) + w.z; aA.w += b2f(xa0.w) + w.w;
                }
                if (remA > 1) {
                    const float4 w = *(const float4*)&v[(size_t)qa1 * H_DIM + lane * 4];
                    aA.x += b2f(xa1.x) + w.x; aA.y += b2f(xa1.y) + w.y;
                    aA.z += b2f(xa1.z) + w.z; aA.w += b2f(xa1.w) + w.w;
                }
                if (remA > 2) {
                    const float4 w = *(const float4*)&v[(size_t)qa2 * H_DIM + lane * 4];
                    aA.x += b2f(xa2.x) + w.x; aA.y += b2f(xa2.y) + w.y;
                    aA.z += b2f(xa2.z) + w.z; aA.w += b2f(xa2.w) + w.w;
                }
                if (remA > 3) {
                    const float4 w = *(const float4*)&v[(size_t)qa3 * H_DIM + lane * 4];
                    aA.x += b2f(xa3.x) + w.x; aA.y += b2f(xa3.y) + w.y;
                    aA.z += b2f(xa3.z) + w.z; aA.w += b2f(xa3.w) + w.w;
                }
                if (remB > 0) {
                    const float4 w = *(const float4*)&v[(size_t)qb0 * H_DIM + lane * 4];
                    aB.x += b2f(xb0.x) + w.x; aB.y += b2f(xb0.y) + w.y;
                    aB.z += b2f(xb0.z) + w.z; aB.w += b2f(xb0.w) + w.w;
                }
                if (remB > 1) {
                    const float4 w = *(const float4*)&v[(size_t)qb1 * H_DIM + lane * 4];
                    aB.x += b2f(xb1.x) + w.x; aB.y += b2f(xb1.y) + w.y;
                    aB.z += b2f(xb1.z) + w.z; aB.w += b2f(xb1.w) + w.w;
                }
                if (remB > 2) {
                    const float4 w = *(const float4*)&v[(size_t)qb2 * H_DIM + lane * 4];
                    aB.x += b2f(xb2.x) + w.x; aB.y += b2f(xb2.y) + w.y;
                    aB.z += b2f(xb2.z) + w.z; aB.w += b2f(xb2.w) + w.w;
                }
                if (remB > 3) {
                    const float4 w = *(const float4*)&v[(size_t)qb3 * H_DIM + lane * 4];
                    aB.x += b2f(xb3.x) + w.x; aB.y += b2f(xb3.y) + w.y;
                    aB.z += b2f(xb3.z) + w.z; aB.w += b2f(xb3.w) + w.w;
                }
            }
            us4 oA = { f2b(aA.x), f2b(aA.y), f2b(aA.z), f2b(aA.w) };
            us4 oB = { f2b(aB.x), f2b(aB.y), f2b(aB.z), f2b(aB.w) };
            *(us4*)(Ub + lrA * 512 + ((lane * 8) ^ ((lrA & 7) << 4))) = oA;
            *(us4*)(Ub + lrB * 512 + ((lane * 8) ^ ((lrB & 7) << 4))) = oB;
        }
    }
    __syncthreads();

    f32x4 acc[2][4];
    #pragma unroll
    for (int i = 0; i < 2; ++i)
        #pragma unroll
        for (int j = 0; j < 4; ++j) acc[i][j] = (f32x4){0.f, 0.f, 0.f, 0.f};

    // A-fragment addressing (shared by both GEMMs)
    const int rowb0 = l15 * 512;
    const int rowb1 = (16 + l15) * 512;
    const int xorv = (l15 & 7) << 4;
    // B-fragment base: lane-contiguous fragment tiles in L2
    const unsigned short* wb1 = Wf1 + ((size_t)(wc * 4) * 64 + lane) * 8;
    const unsigned short* wb2 = Wf2 + ((size_t)(wc * 4) * 64 + lane) * 8;

    // ---------------- GEMM1 (no barriers) ----------------
    #pragma unroll 2
    for (int kb = 0; kb < 8; ++kb) {
        const int c0 = (kb * 64 + q * 16) ^ xorv;
        const short8 av0 = *(const short8*)(Ub + rowb0 + c0);
        const short8 av1 = *(const short8*)(Ub + rowb1 + c0);
        #pragma unroll
        for (int ni = 0; ni < 4; ++ni) {
            const short8 bv = *(const short8*)&wb1[(size_t)kb * 8192 + ni * 512];
            acc[0][ni] = __builtin_amdgcn_mfma_f32_16x16x32_bf16(av0, bv, acc[0][ni], 0, 0, 0);
            acc[1][ni] = __builtin_amdgcn_mfma_f32_16x16x32_bf16(av1, bv, acc[1][ni], 0, 0, 0);
        }
    }
    __syncthreads();   // all waves done reading z from U

    // bias + relu -> U (same swizzled layout)
    #pragma unroll
    for (int ni = 0; ni < 4; ++ni) {
        const int col = wc * 64 + ni * 16 + l15;
        const float bb = b1[col];
        #pragma unroll
        for (int mi = 0; mi < 2; ++mi)
            #pragma unroll
            for (int j = 0; j < 4; ++j) {
                const int row = mi * 16 + q * 4 + j;
                const int tb = row * 512 + ((col * 2) ^ ((row & 7) << 4));
                *(unsigned short*)(Ub + tb) = f2b(fmaxf(acc[mi][ni][j] + bb, 0.f));
            }
    }
    #pragma unroll
    for (int i = 0; i < 2; ++i)
        #pragma unroll
        for (int j = 0; j < 4; ++j) acc[i][j] = (f32x4){0.f, 0.f, 0.f, 0.f};
    __syncthreads();

    // ---------------- GEMM2 (no barriers) ----------------
    #pragma unroll 2
    for (int kb = 0; kb < 8; ++kb) {
        const int c0 = (kb * 64 + q * 16) ^ xorv;
        const short8 av0 = *(const short8*)(Ub + rowb0 + c0);
        const short8 av1 = *(const short8*)(Ub + rowb1 + c0);
        #pragma unroll
        for (int ni = 0; ni < 4; ++ni) {
            const short8 bv = *(const short8*)&wb2[(size_t)kb * 8192 + ni * 512];
            acc[0][ni] = __builtin_amdgcn_mfma_f32_16x16x32_bf16(av0, bv, acc[0][ni], 0, 0, 0);
            acc[1][ni] = __builtin_amdgcn_mfma_f32_16x16x32_bf16(av1, bv, acc[1][ni], 0, 0, 0);
        }
    }

    // ---------------- epilogue: Hout + pooled column sums ----------------
    int cols[4]; float b2c[4], vc[4];
    #pragma unroll
    for (int ni = 0; ni < 4; ++ni) {
        cols[ni] = wc * 64 + ni * 16 + l15;
        b2c[ni] = b2[cols[ni]];
        vc[ni]  = vg[cols[ni]];
    }
    float lsum[4] = {0.f, 0.f, 0.f, 0.f};
    #pragma unroll
    for (int mi = 0; mi < 2; ++mi)
        #pragma unroll
        for (int j = 0; j < 4; ++j) {
            const int row = m0 + mi * 16 + q * 4 + j;
            const unsigned short* hip_ = &Hin[(size_t)row * H_DIM];
            unsigned short* hop = &Hout[(size_t)row * H_DIM];
            #pragma unroll
            for (int ni = 0; ni < 4; ++ni) {
                const float val = b2f(hip_[cols[ni]]) + vc[ni]
                                + acc[mi][ni][j] + b2c[ni];
                hop[cols[ni]] = f2b(val);
                lsum[ni] += val;
            }
        }
    #pragma unroll
    for (int ni = 0; ni < 4; ++ni) atomicAdd(&hl[cols[ni]], lsum[ni]);
    __syncthreads();
    atomicAdd(&hsum[(size_t)bq0 * H_DIM + tid], hl[tid]);
}

// ----------------------------------------------------- small fp32 GEMM -----
template<bool RELU>
__global__ __launch_bounds__(256) void gemm_small_kernel(
    const float* __restrict__ A, const float* __restrict__ W,
    const float* __restrict__ bias, float* __restrict__ C,
    int M, int N, int K)
{
    constexpr int BM = 32, BN = 64, BK = 32, TM = 2;
    __shared__ __align__(16) float As[BK][BM + 4];
    __shared__ __align__(16) float Bs[BK][BN];
    const int tid = threadIdx.x;
    const int tx = tid & 15;
    const int ty = tid >> 4;
    const int m0 = blockIdx.x * BM;
    const int n0 = blockIdx.y * BN;

    float acc[TM][4] = {};

    for (int kt = 0; kt < K; kt += BK) {
        {
            const int row = tid >> 3, kq = tid & 7;
            const float4 a = *(const float4*)&A[(size_t)(m0 + row) * K + kt + kq * 4];
            As[kq * 4 + 0][row] = a.x;
            As[kq * 4 + 1][row] = a.y;
            As[kq * 4 + 2][row] = a.z;
            As[kq * 4 + 3][row] = a.w;
        }
        #pragma unroll
        for (int i = 0; i < 2; ++i) {
            const int f = tid + i * 256;
            const int row = f >> 4, c4 = f & 15;
            *(float4*)&Bs[row][c4 * 4] =
                *(const float4*)&W[(size_t)(kt + row) * N + n0 + c4 * 4];
        }
        __syncthreads();
        #pragma unroll
        for (int kk = 0; kk < BK; ++kk) {
            const float4 bv = *(const float4*)&Bs[kk][tx * 4];
            #pragma unroll
            for (int im = 0; im < TM; ++im) {
                const float a = As[kk][ty * TM + im];
                acc[im][0] += a * bv.x; acc[im][1] += a * bv.y;
                acc[im][2] += a * bv.z; acc[im][3] += a * bv.w;
            }
        }
        __syncthreads();
    }

    const float4 bb = *(const float4*)&bias[n0 + tx * 4];
    #pragma unroll
    for (int im = 0; im < TM; ++im) {
        const int m = m0 + ty * TM + im;
        float4 r;
        r.x = acc[im][0] + bb.x; r.y = acc[im][1] + bb.y;
        r.z = acc[im][2] + bb.z; r.w = acc[im][3] + bb.w;
        if constexpr (RELU) {
            r.x = fmaxf(r.x, 0.f); r.y = fmaxf(r.y, 0.f);
            r.z = fmaxf(r.z, 0.f); r.w = fmaxf(r.w, 0.f);
        }
        *(float4*)&C[(size_t)m * N + n0 + tx * 4] = r;
    }
}

// ------------------------------------------------- readout from hsum -------
__global__ __launch_bounds__(256) void pool_hsum_kernel(
    const float* __restrict__ hl, const float* __restrict__ hp,
    float* __restrict__ comb)
{
    const int b = blockIdx.x, n = threadIdx.x;
    comb[(size_t)b * 512 + n]       = hl[(size_t)b * H_DIM + n] * (1.f / 64.f);
    comb[(size_t)b * 512 + 256 + n] = hp[(size_t)b * H_DIM + n] * (1.f / 128.f);
}

// ------------------------------------------------------------ final dot ----
__global__ __launch_bounds__(256) void pred_final_kernel(
    const float* __restrict__ hidden, const float* __restrict__ W2,
    const float* __restrict__ b2, float* __restrict__ out)
{
    const int b = blockIdx.x, t = threadIdx.x;
    float p = hidden[(size_t)b * H_DIM + t] * W2[t];
    #pragma unroll
    for (int off = 32; off >= 1; off >>= 1) p += __shfl_down(p, off);
    __shared__ float red[4];
    if ((t & 63) == 0) red[t >> 6] = p;
    __syncthreads();
    if (t == 0) out[b] = red[0] + red[1] + red[2] + red[3] + b2[0];
}

// ===========================================================================
extern "C" void kernel_launch(void* const* d_in, const int* in_sizes, int n_in,
                              void* d_out, int out_size, void* d_ws, size_t ws_size,
                              hipStream_t stream)
{
    const int NL = 65536, NP = 131072, EL = 262144, EP = 524288;
    const int B = BGRAPH, H = H_DIM;

    const float* lig_x        = (const float*)d_in[0];
    const float* prot_x       = (const float*)d_in[1];
    const float* lig_embed_W  = (const float*)d_in[2];
    const float* lig_embed_b  = (const float*)d_in[3];
    const float* prot_embed_W = (const float*)d_in[4];
    const float* prot_embed_b = (const float*)d_in[5];
    const float* lig_virtual0 = (const float*)d_in[6];
    const float* prot_virtual0= (const float*)d_in[7];
    const float* lig_conv_W1  = (const float*)d_in[8];
    const float* lig_conv_b1  = (const float*)d_in[9];
    const float* lig_conv_W2  = (const float*)d_in[10];
    const float* lig_conv_b2  = (const float*)d_in[11];
    const float* lig_vmlp_W   = (const float*)d_in[12];
    const float* lig_vmlp_b   = (const float*)d_in[13];
    const float* lig_vmlp_g   = (const float*)d_in[14];
    const float* lig_vmlp_be  = (const float*)d_in[15];
    const float* prot_conv_W1 = (const float*)d_in[16];
    const float* prot_conv_b1 = (const float*)d_in[17];
    const float* prot_conv_W2 = (const float*)d_in[18];
    const float* prot_conv_b2 = (const float*)d_in[19];
    const float* prot_vmlp_W  = (const float*)d_in[20];
    const float* prot_vmlp_b  = (const float*)d_in[21];
    const float* prot_vmlp_g  = (const float*)d_in[22];
    const float* prot_vmlp_be = (const float*)d_in[23];
    const float* pred_W1      = (const float*)d_in[24];
    const float* pred_b1      = (const float*)d_in[25];
    const float* pred_W2      = (const float*)d_in[26];
    const float* pred_b2      = (const float*)d_in[27];
    const int* lig_batch      = (const int*)d_in[28];
    const int* prot_batch     = (const int*)d_in[29];
    const int* lig_ei         = (const int*)d_in[30];
    const int* prot_ei        = (const int*)d_in[31];

    // ---- workspace layout (~233 MB) ----
    float* ws = (float*)d_ws;
    float* lig_v    = ws;                          // B*H
    float* prot_v   = lig_v    + (size_t)B * H;    // B*H
    float* vtmpL    = prot_v   + (size_t)B * H;    // B*H
    float* vtmpP    = vtmpL    + (size_t)B * H;    // B*H
    float* part     = vtmpP    + (size_t)B * H;    // 2*2*256 = 1024
    float* comb     = part     + 1024;             // B*2H
    float* hidden   = comb     + (size_t)B * 2 * H;// B*H
    float* hsum_lig = hidden   + (size_t)B * H;    // B*H  (contiguous with
    float* hsum_prot= hsum_lig + (size_t)B * H;    //  hsum_prot for 1 memset)
    unsigned short* lig_h0  = (unsigned short*)(hsum_prot + (size_t)B * H);
    unsigned short* lig_h1  = lig_h0  + (size_t)NL * H;
    unsigned short* prot_h0 = lig_h1  + (size_t)NL * H;
    unsigned short* prot_h1 = prot_h0 + (size_t)NP * H;
    unsigned short* wf_lw1  = prot_h1 + (size_t)NP * H;   // 5*H*H each
    unsigned short* wf_lw2  = wf_lw1 + (size_t)NLAYER * H * H;
    unsigned short* wf_pw1  = wf_lw2 + (size_t)NLAYER * H * H;
    unsigned short* wf_pw2  = wf_pw1 + (size_t)NLAYER * H * H;
    int* deg_lig  = (int*)(wf_pw2 + (size_t)NLAYER * H * H); // NL
    int* deg_prot = deg_lig  + NL;                   // NP
    int* bkt_lig  = deg_prot + NP;                   // NL*CAP
    int* bkt_prot = bkt_lig  + (size_t)NL * CAP;     // NP*CAP

    // ---- one-time-per-call prep ----
    hipMemsetAsync(deg_lig, 0, (size_t)(NL + NP) * sizeof(int), stream);
    bucket_build_kernel<<<EL / 256, 256, 0, stream>>>(
        lig_ei, lig_ei + EL, EL, deg_lig, bkt_lig);
    bucket_build_kernel<<<EP / 256, 256, 0, stream>>>(
        prot_ei, prot_ei + EP, EP, deg_prot, bkt_prot);
    wprep_kernel<<<dim3(8, 16, NLAYER), 64, 0, stream>>>(lig_conv_W1, wf_lw1);
    wprep_kernel<<<dim3(8, 16, NLAYER), 64, 0, stream>>>(lig_conv_W2, wf_lw2);
    wprep_kernel<<<dim3(8, 16, NLAYER), 64, 0, stream>>>(prot_conv_W1, wf_pw1);
    wprep_kernel<<<dim3(8, 16, NLAYER), 64, 0, stream>>>(prot_conv_W2, wf_pw2);

    // ---- embeddings + pool0 ----
    embed_kernel<<<NL / 8, 256, 0, stream>>>(lig_x, lig_embed_W, lig_embed_b, lig_h0, 26);
    embed_kernel<<<NP / 8, 256, 0, stream>>>(prot_x, prot_embed_W, prot_embed_b, prot_h0, 20);
    init_v_kernel<<<B, 256, 0, stream>>>(lig_virtual0, prot_virtual0, lig_v, prot_v);
    pool0_kernel<<<dim3(B, 2), 256, 0, stream>>>(lig_h0, prot_h0, hsum_lig, hsum_prot);

    for (int i = 0; i < NLAYER; ++i) {
        const size_t wo = (size_t)i * H * H;
        const size_t bo = (size_t)i * H;
        unsigned short* lin  = (i & 1) ? lig_h1  : lig_h0;
        unsigned short* lout = (i & 1) ? lig_h0  : lig_h1;
        unsigned short* pin  = (i & 1) ? prot_h1 : prot_h0;
        unsigned short* pout = (i & 1) ? prot_h0 : prot_h1;

        hipMemsetAsync(part, 0, 1024 * sizeof(float), stream);
        vmlp_gemm_kernel<<<dim3(32, 4, 2), 256, 0, stream>>>(
            lig_v, hsum_lig, lig_vmlp_W + wo, lig_vmlp_b + bo,
            prot_v, hsum_prot, prot_vmlp_W + wo, prot_vmlp_b + bo,
            vtmpL, vtmpP, part);
        vmlp_apply_kernel<<<dim3(256, 2), 256, 0, stream>>>(
            part, lig_vmlp_g + bo, lig_vmlp_be + bo,
            prot_vmlp_g + bo, prot_vmlp_be + bo,
            vtmpL, vtmpP, lig_v, prot_v);
        hipMemsetAsync(hsum_lig, 0, (size_t)2 * B * H * sizeof(float), stream);
        conv_fused4_kernel<<<NL / 32, 256, 0, stream>>>(
            lin, deg_lig, bkt_lig, lig_batch, lig_v,
            wf_lw1 + wo, lig_conv_b1 + bo, wf_lw2 + wo, lig_conv_b2 + bo,
            lout, hsum_lig);
        conv_fused4_kernel<<<NP / 32, 256, 0, stream>>>(
            pin, deg_prot, bkt_prot, prot_batch, prot_v,
            wf_pw1 + wo, prot_conv_b1 + bo, wf_pw2 + wo, prot_conv_b2 + bo,
            pout, hsum_prot);
    }

    // ---- readout ----
    pool_hsum_kernel<<<B, 256, 0, stream>>>(hsum_lig, hsum_prot, comb);
    gemm_small_kernel<true><<<dim3(B / 32, 4), 256, 0, stream>>>(
        comb, pred_W1, pred_b1, hidden, B, H, 2 * H);
    pred_final_kernel<<<B, 256, 0, stream>>>(hidden, pred_W2, pred_b2, (float*)d_out);
}